// Round 12
// baseline (526.463 us; speedup 1.0000x reference)
//
#include <hip/hip_runtime.h>
#include <cfloat>
#include <math.h>

// Exact-replication KNN (k=10, +self) + rank-column gather max-pool.
// NUMERICS FROZEN (R3 pass, absmax 0.0): fp32 chains
//   sq  = fma(z,z, fma(y,y, rn(x*x)))
//   dot = fma(z,z', fma(y,y', rn(x*x')))
//   d   = fma(dot, -2, rn(sq_i+sq_j))    [== rn(sum - rn(2*dot)), 2*dot exact]
// Selection order = jax top_k = ascending lexicographic (d, orig_idx).
//
// Round 12: remove the wave-serial pop/insert loop entirely.
//  - Candidate key = (sortable_u32(d) << 32) | orig_idx. u64 order == lex
//    (d, idx) order (d never -0.0: all-positive chains). Each lane keeps a
//    PRIVATE sorted top-11 (11 u64 regs, branchless shift-insert, fully
//    lane-parallel; ballot-skipped when nothing passes). Exact: a candidate
//    outside its lane's top-11 has >=11 lex-smaller in that lane alone.
//  - Tile-skip bound: any lane's local 11th >= global 11th, so
//    wb = min(seed, wave_min(hi32(L[10]))) is sound (one u32-min butterfly
//    per TILE — R11's per-tile serial extract chain is gone).
//  - Final merge: 11 rounds of wave-min-u64 extraction (keys unique) ->
//    ranks 0..10; rank 0 dropped positionally; epilogue unchanged.
//  - 1 query per wave: 32768 waves = 4x resident slots -> real refill;
//    straggler waves are 4x smaller and latency is lane-parallel now.
// Survivor build covers offsets +-1..128 (g<4) — R11's g<2 hole avoided.

#define N_PTS    16384
#define C_FEAT   64
#define KK       11
#define NCELLS   4096                 // 16^3 Morton cells
#define TILE     128                  // sorted points per tile
#define NTILES   (N_PTS / TILE)       // 128
#define NWAVES   4
#define NTHREADS (NWAVES * 64)
#define SENTU64  0xFFFFFFFFFFFFFFFFull

// d_ws layout (bytes)
#define WS_CAND  0                          // float4[2][N_PTS]   512 KB
#define WS_AABB  (WS_CAND + 2*N_PTS*16)     // float[2][NTILES][6]

__device__ __forceinline__ unsigned sortkey32(unsigned b) {
    return b ^ ((unsigned)((int)b >> 31) | 0x80000000u);
}

__device__ __forceinline__ int cell_of(float x, float y, float z) {
    int cx = (int)floorf((x + 4.5f) * (16.0f / 9.0f));
    int cy = (int)floorf((y + 4.5f) * (16.0f / 9.0f));
    int cz = (int)floorf((z + 4.5f) * (16.0f / 9.0f));
    cx = min(15, max(0, cx));
    cy = min(15, max(0, cy));
    cz = min(15, max(0, cz));
    int m = 0;
    #pragma unroll
    for (int b = 0; b < 4; ++b)
        m |= (((cx >> b) & 1) << (3 * b)) |
             (((cy >> b) & 1) << (3 * b + 1)) |
             (((cz >> b) & 1) << (3 * b + 2));
    return m;
}

// Fused hist + scan + scatter. One block per instance, 1024 threads.
__global__ __launch_bounds__(1024) void sort_kernel(
    const float* __restrict__ src_c, const float* __restrict__ tgt_c,
    float4* __restrict__ cand)
{
    const int inst = blockIdx.x;
    const float* __restrict__ coords = inst ? tgt_c : src_c;
    float4* __restrict__ cb = cand + inst * N_PTS;

    __shared__ int hist[NCELLS];   // becomes running write-pointer after scan
    __shared__ int sd[1024];
    const int t = threadIdx.x;

    for (int i = t; i < NCELLS; i += 1024) hist[i] = 0;
    __syncthreads();

    int mycell[16];
    #pragma unroll
    for (int j = 0; j < 16; ++j) {
        const int p = j * 1024 + t;
        const float* c = coords + (size_t)p * 3;
        mycell[j] = cell_of(c[0], c[1], c[2]);
        atomicAdd(&hist[mycell[j]], 1);
    }
    __syncthreads();

    int v[4], ssum = 0;
    #pragma unroll
    for (int j = 0; j < 4; ++j) { v[j] = hist[t * 4 + j]; ssum += v[j]; }
    sd[t] = ssum;
    __syncthreads();
    for (int off = 1; off < 1024; off <<= 1) {
        const int x = (t >= off) ? sd[t - off] : 0;
        __syncthreads();
        sd[t] += x;
        __syncthreads();
    }
    int base = sd[t] - ssum;
    #pragma unroll
    for (int j = 0; j < 4; ++j) { hist[t * 4 + j] = base; base += v[j]; }
    __syncthreads();

    #pragma unroll
    for (int j = 0; j < 16; ++j) {
        const int p = j * 1024 + t;
        const float* c = coords + (size_t)p * 3;
        const int dst = atomicAdd(&hist[mycell[j]], 1);
        cb[dst] = make_float4(c[0], c[1], c[2], __int_as_float(p));
    }
}

__global__ void aabb_kernel(const float4* __restrict__ cand,
                            float* __restrict__ aabb) {
    const int it = blockIdx.x;                 // inst*NTILES + tile
    const int base = (it / NTILES) * N_PTS + (it % NTILES) * TILE;
    const int lane = threadIdx.x;              // 64 threads, 2 pts each
    float4 a = cand[base + lane], b = cand[base + 64 + lane];
    float mnx = fminf(a.x, b.x), mny = fminf(a.y, b.y), mnz = fminf(a.z, b.z);
    float mxx = fmaxf(a.x, b.x), mxy = fmaxf(a.y, b.y), mxz = fmaxf(a.z, b.z);
    #pragma unroll
    for (int off = 1; off < 64; off <<= 1) {
        mnx = fminf(mnx, __shfl_xor(mnx, off));
        mny = fminf(mny, __shfl_xor(mny, off));
        mnz = fminf(mnz, __shfl_xor(mnz, off));
        mxx = fmaxf(mxx, __shfl_xor(mxx, off));
        mxy = fmaxf(mxy, __shfl_xor(mxy, off));
        mxz = fmaxf(mxz, __shfl_xor(mxz, off));
    }
    if (lane == 0) {
        aabb[it * 6 + 0] = mnx; aabb[it * 6 + 1] = mny; aabb[it * 6 + 2] = mnz;
        aabb[it * 6 + 3] = mxx; aabb[it * 6 + 4] = mxy; aabb[it * 6 + 5] = mxz;
    }
}

// One 64-candidate batch vs this wave's single query. Per-lane top-11
// insert; no cross-lane ops except the ballot skip (and the one-time seed).
#define PB(C, INIT)                                                         \
  {                                                                         \
    const float cx = (C).x, cy = (C).y, cz = (C).z;                         \
    const int cor = __float_as_int((C).w);                                  \
    const float csq = __fmaf_rn(cz, cz, __fmaf_rn(cy, cy,                   \
                                __fmul_rn(cx, cx)));                        \
    float dot = __fmul_rn(cx, qx);                                          \
    dot = __fmaf_rn(cy, qy, dot);                                           \
    dot = __fmaf_rn(cz, qz, dot);                                           \
    const float sum = __fadd_rn(qsq, csq);                                  \
    const float d = __fmaf_rn(dot, -2.0f, sum);                             \
    if (INIT) {                                                             \
      float t16 = d;                                                        \
      _Pragma("unroll")                                                     \
      for (int off = 1; off < 16; off <<= 1)                                \
        t16 = fmaxf(t16, __shfl_xor(t16, off));                             \
      wseedf = __int_as_float(__builtin_amdgcn_readlane(                    \
          __float_as_int(t16), 0));   /* max of 16 cands >= global 11th */  \
      useed = sortkey32(__float_as_uint(wseedf));                           \
    }                                                                       \
    const unsigned ub = __float_as_uint(d);                                 \
    const unsigned uk = sortkey32(ub);                                      \
    const unsigned long long k =                                            \
        ((unsigned long long)uk << 32) | (unsigned)cor;                     \
    const bool pass = k < L[10];                                            \
    if (__ballot(pass)) {                                                   \
      if (pass) {                                                           \
        _Pragma("unroll")                                                   \
        for (int i = 10; i >= 1; --i)                                       \
          L[i] = (k < L[i]) ? ((k < L[i-1]) ? L[i-1] : k) : L[i];           \
        L[0] = (k < L[0]) ? k : L[0];                                       \
      }                                                                     \
    }                                                                       \
  }

__global__ __launch_bounds__(NTHREADS) void knn_pool_kernel(
    const float* __restrict__ src_f, const float* __restrict__ tgt_f,
    const float4* __restrict__ cand, const float* __restrict__ aabb,
    float* __restrict__ out)
{
    const int inst = blockIdx.x & 1;
    const float* __restrict__ feats = inst ? tgt_f : src_f;
    float* __restrict__ outb = out + (size_t)inst * N_PTS * (2 * C_FEAT);
    const float4* __restrict__ cd = cand + inst * N_PTS;

    const int tid = threadIdx.x, wave = tid >> 6, lane = tid & 63;

    __shared__ float sab[NTILES * 6];                 // 3 KB
    __shared__ unsigned slist[NWAVES][NTILES];        // 2 KB
    for (int i = tid; i < NTILES * 6; i += NTHREADS)
        sab[i] = aabb[inst * NTILES * 6 + i];
    __syncthreads();

    // One query per wave.
    const int qidx = (blockIdx.x >> 1) * NWAVES + wave;   // sorted row
    const float4 qc = cd[qidx];
    const float qx = qc.x, qy = qc.y, qz = qc.z;
    const int qor = __float_as_int(qc.w);
    const float qsq = __fmaf_rn(qz, qz, __fmaf_rn(qy, qy, __fmul_rn(qx, qx)));

    unsigned long long L[11];        // per-lane sorted top-11 (u64 lex keys)
    #pragma unroll
    for (int i = 0; i < 11; ++i) L[i] = SENTU64;
    float wseedf = FLT_MAX;
    unsigned useed = 0xFFFFFFFFu;

    const int ownt = qidx / TILE;    // tile containing this query

    // ---- own tile first (fills lists, seeds the bound) ----
    {
        const float4 c0 = cd[ownt * TILE + lane];
        const float4 c1 = cd[ownt * TILE + 64 + lane];
        PB(c0, true);
        PB(c1, false);
    }

    // ---- zigzag survivor list (offsets +-1..128 around ownt) ----
    int nsurv = 0;
    #pragma unroll
    for (int g = 0; g < 4; ++g) {
        const int p = g * 64 + lane;
        const int o = (p >> 1) + 1;
        const int t = (p & 1) ? (ownt - o) : (ownt + o);
        bool ok = (t >= 0) && (t < NTILES);
        float lb = 0.0f;
        if (ok) {
            const float dx = fmaxf(0.f, fmaxf(sab[t*6+0] - qx, qx - sab[t*6+3]));
            const float dy = fmaxf(0.f, fmaxf(sab[t*6+1] - qy, qy - sab[t*6+4]));
            const float dz = fmaxf(0.f, fmaxf(sab[t*6+2] - qz, qz - sab[t*6+5]));
            lb = dx * dx;
            lb = fmaf(dy, dy, lb);
            lb = fmaf(dz, dz, lb);
            ok = (lb - 1e-3f) <= wseedf;   // margin >> fp32 chain error
        }
        const unsigned long long mk = __ballot(ok);
        if (ok) {
            const int idx = nsurv + (int)__popcll(mk & ((1ull << lane) - 1ull));
            slist[wave][idx] = (__float_as_uint(lb) & 0xFFFFFF00u) | (unsigned)t;
        }
        nsurv += (int)__popcll(mk);
    }

    // ---- scan survivors: ping-pong prefetch + live recheck per tile ----
    float4 A0, A1, B0, B1;
    unsigned uA = 0, uB = 0;
    {
        uA = (0 < nsurv) ? slist[wave][0] : (unsigned)ownt;
        const int ta = (int)(uA & 0xFFu);
        A0 = cd[ta * TILE + lane]; A1 = cd[ta * TILE + 64 + lane];
        uB = (1 < nsurv) ? slist[wave][1] : (unsigned)ownt;
        const int tb = (int)(uB & 0xFFu);
        B0 = cd[tb * TILE + lane]; B1 = cd[tb * TILE + 64 + lane];
    }
    int s = 0;
    while (s < nsurv) {
        {
            // current bound: min over lanes of local 11th (ukey), + seed.
            unsigned h = (unsigned)(L[10] >> 32);
            #pragma unroll
            for (int off = 1; off < 64; off <<= 1)
                h = min(h, (unsigned)__shfl_xor((int)h, off));
            const unsigned wb = min(useed, h);
            const unsigned uN = (s + 2 < nsurv) ? slist[wave][s + 2]
                                                : (unsigned)ownt;
            const int tn = (int)(uN & 0xFFu);
            const float lbf = __uint_as_float(uA & 0xFFFFFF00u);
            if (sortkey32(__float_as_uint(__fsub_rn(lbf, 1e-3f))) <= wb) {
                PB(A0, false);
                PB(A1, false);
            }
            uA = uN;
            A0 = cd[tn * TILE + lane]; A1 = cd[tn * TILE + 64 + lane];
            ++s;
            if (s >= nsurv) break;
        }
        {
            unsigned h = (unsigned)(L[10] >> 32);
            #pragma unroll
            for (int off = 1; off < 64; off <<= 1)
                h = min(h, (unsigned)__shfl_xor((int)h, off));
            const unsigned wb = min(useed, h);
            const unsigned uN = (s + 2 < nsurv) ? slist[wave][s + 2]
                                                : (unsigned)ownt;
            const int tn = (int)(uN & 0xFFu);
            const float lbf = __uint_as_float(uB & 0xFFFFFF00u);
            if (sortkey32(__float_as_uint(__fsub_rn(lbf, 1e-3f))) <= wb) {
                PB(B0, false);
                PB(B1, false);
            }
            uB = uN;
            B0 = cd[tn * TILE + lane]; B1 = cd[tn * TILE + 64 + lane];
            ++s;
        }
    }

    // ---- exact merge: 11 rounds of wave-min extraction (unique keys) ----
    int gidx = 0;
    #pragma unroll
    for (int r = 0; r < KK; ++r) {
        unsigned long long mk = L[0];
        #pragma unroll
        for (int off = 1; off < 64; off <<= 1) {
            const unsigned long long o = __shfl_xor(mk, off);
            mk = (o < mk) ? o : mk;
        }
        if (lane == r) gidx = (int)(unsigned)mk;   // rank r's orig index
        if (L[0] == mk) {                          // unique owner shifts
            #pragma unroll
            for (int i = 0; i < 10; ++i) L[i] = L[i + 1];
            L[10] = SENTU64;
        }
    }

    // Rank 0 (lex-smallest: self or -1ulp near-twin) dropped positionally.
    // Ranks 1..10 -> feature columns 0..9.
    float fv = (lane >= 1 && lane < KK)
                   ? feats[(size_t)gidx * C_FEAT + (lane - 1)] : -FLT_MAX;
    #pragma unroll
    for (int off = 1; off < 64; off <<= 1)
        fv = fmaxf(fv, __shfl_xor(fv, off));       // M in all lanes

    const int row = qor;
    const float v = feats[(size_t)row * C_FEAT + lane];
    outb[(size_t)row * (2 * C_FEAT) + lane]          = v;
    outb[(size_t)row * (2 * C_FEAT) + C_FEAT + lane] = fv - v;
}

extern "C" void kernel_launch(void* const* d_in, const int* in_sizes, int n_in,
                              void* d_out, int out_size, void* d_ws, size_t ws_size,
                              hipStream_t stream) {
    const float* src_f = (const float*)d_in[0];
    const float* tgt_f = (const float*)d_in[1];
    const float* src_c = (const float*)d_in[2];
    const float* tgt_c = (const float*)d_in[3];
    float* out = (float*)d_out;

    char* ws = (char*)d_ws;
    float4* cand = (float4*)(ws + WS_CAND);
    float*  aabb = (float*) (ws + WS_AABB);

    hipLaunchKernelGGL(sort_kernel, dim3(2), dim3(1024), 0, stream,
                       src_c, tgt_c, cand);
    hipLaunchKernelGGL(aabb_kernel, dim3(2 * NTILES), dim3(64), 0, stream,
                       cand, aabb);
    // 1 query per wave, 4 waves per block: 8192 blocks (4x resident slots).
    hipLaunchKernelGGL(knn_pool_kernel, dim3(2 * (N_PTS / NWAVES)),
                       dim3(NTHREADS), 0, stream, src_f, tgt_f, cand, aabb, out);
}

// Round 13
// 339.944 us; speedup vs baseline: 1.5487x; 1.5487x over previous
//
#include <hip/hip_runtime.h>
#include <cfloat>
#include <math.h>

// Exact-replication KNN (k=10, +self) + rank-column gather max-pool.
// NUMERICS FROZEN (R3 pass, absmax 0.0): fp32 chains
//   sq  = fma(z,z, fma(y,y, rn(x*x)))
//   dot = fma(z,z', fma(y,y', rn(x*x')))
//   d   = fma(dot, -2, rn(sq_i+sq_j))    [== rn(sum - rn(2*dot)), 2*dot exact]
// Selection order = jax top_k = ascending lexicographic (d, orig_idx) —
// proven order-independent in R8-R10 (absmax 0.0, nondeterministic sort).
//
// Round 13: R10 champion structure (pop/insert restored — R11/R12 proved
// alternatives cost more issue slots than the rare pops) + three fixes for
// the 78us idle gap (R10: 82us busy vs 160us wall):
//  1. Persistent waves + atomic work queue (4-query chunks): stragglers no
//     longer pin a wave while the grid drains. Queue is load-balancing only
//     (no inter-block waits, no ordering assumption). Counter reset by
//     hipMemsetAsync each launch.
//  2. Seed = 11th-of-16 via 16-lane bitonic (subset 11th >= global 11th,
//     sound) instead of max-of-16 -> fewer own-tile pops, tighter gate.
//  3. Survivor list sorted by lb (64-lane bitonic, ~85 insts) -> ascending
//     lb scan (R11's order without its serial extraction); live recheck
//     becomes an early BREAK when nsurv<=64 (sound: lb ascending, wmax
//     monotone tightening).

#define N_PTS    16384
#define C_FEAT   64
#define KK       11
#define NCELLS   4096                 // 16^3 Morton cells
#define TILE     128                  // sorted points per tile
#define NTILES   (N_PTS / TILE)       // 128
#define WQ       4
#define NWAVES   4
#define NTHREADS (NWAVES * 64)
#define NCHUNKS  (2 * (N_PTS / WQ))   // 8192 (4096 per instance)
#define SENT32   0xFFFFFFFFu

// d_ws layout (bytes)
#define WS_CAND  0                          // float4[2][N_PTS]   512 KB
#define WS_AABB  (WS_CAND + 2*N_PTS*16)     // float[2][NTILES][6] 6 KB
#define WS_CTR   (WS_AABB + 2*NTILES*6*4)   // int                 8 B

__device__ __forceinline__ int cell_of(float x, float y, float z) {
    int cx = (int)floorf((x + 4.5f) * (16.0f / 9.0f));
    int cy = (int)floorf((y + 4.5f) * (16.0f / 9.0f));
    int cz = (int)floorf((z + 4.5f) * (16.0f / 9.0f));
    cx = min(15, max(0, cx));
    cy = min(15, max(0, cy));
    cz = min(15, max(0, cz));
    int m = 0;
    #pragma unroll
    for (int b = 0; b < 4; ++b)
        m |= (((cx >> b) & 1) << (3 * b)) |
             (((cy >> b) & 1) << (3 * b + 1)) |
             (((cz >> b) & 1) << (3 * b + 2));
    return m;
}

// Fused hist + scan + scatter. One block per instance, 1024 threads.
__global__ __launch_bounds__(1024) void sort_kernel(
    const float* __restrict__ src_c, const float* __restrict__ tgt_c,
    float4* __restrict__ cand)
{
    const int inst = blockIdx.x;
    const float* __restrict__ coords = inst ? tgt_c : src_c;
    float4* __restrict__ cb = cand + inst * N_PTS;

    __shared__ int hist[NCELLS];   // becomes running write-pointer after scan
    __shared__ int sd[1024];
    const int t = threadIdx.x;

    for (int i = t; i < NCELLS; i += 1024) hist[i] = 0;
    __syncthreads();

    int mycell[16];
    #pragma unroll
    for (int j = 0; j < 16; ++j) {
        const int p = j * 1024 + t;
        const float* c = coords + (size_t)p * 3;
        mycell[j] = cell_of(c[0], c[1], c[2]);
        atomicAdd(&hist[mycell[j]], 1);
    }
    __syncthreads();

    int v[4], ssum = 0;
    #pragma unroll
    for (int j = 0; j < 4; ++j) { v[j] = hist[t * 4 + j]; ssum += v[j]; }
    sd[t] = ssum;
    __syncthreads();
    for (int off = 1; off < 1024; off <<= 1) {
        const int x = (t >= off) ? sd[t - off] : 0;
        __syncthreads();
        sd[t] += x;
        __syncthreads();
    }
    int base = sd[t] - ssum;
    #pragma unroll
    for (int j = 0; j < 4; ++j) { hist[t * 4 + j] = base; base += v[j]; }
    __syncthreads();

    #pragma unroll
    for (int j = 0; j < 16; ++j) {
        const int p = j * 1024 + t;
        const float* c = coords + (size_t)p * 3;
        const int dst = atomicAdd(&hist[mycell[j]], 1);
        cb[dst] = make_float4(c[0], c[1], c[2], __int_as_float(p));
    }
}

__global__ void aabb_kernel(const float4* __restrict__ cand,
                            float* __restrict__ aabb) {
    const int it = blockIdx.x;                 // inst*NTILES + tile
    const int base = (it / NTILES) * N_PTS + (it % NTILES) * TILE;
    const int lane = threadIdx.x;              // 64 threads, 2 pts each
    float4 a = cand[base + lane], b = cand[base + 64 + lane];
    float mnx = fminf(a.x, b.x), mny = fminf(a.y, b.y), mnz = fminf(a.z, b.z);
    float mxx = fmaxf(a.x, b.x), mxy = fmaxf(a.y, b.y), mxz = fmaxf(a.z, b.z);
    #pragma unroll
    for (int off = 1; off < 64; off <<= 1) {
        mnx = fminf(mnx, __shfl_xor(mnx, off));
        mny = fminf(mny, __shfl_xor(mny, off));
        mnz = fminf(mnz, __shfl_xor(mnz, off));
        mxx = fmaxf(mxx, __shfl_xor(mxx, off));
        mxy = fmaxf(mxy, __shfl_xor(mxy, off));
        mxz = fmaxf(mxz, __shfl_xor(mxz, off));
    }
    if (lane == 0) {
        aabb[it * 6 + 0] = mnx; aabb[it * 6 + 1] = mny; aabb[it * 6 + 2] = mnz;
        aabb[it * 6 + 3] = mxx; aabb[it * 6 + 4] = mxy; aabb[it * 6 + 5] = mxz;
    }
}

// One 64-candidate batch vs the wave's 4 queries (pop/insert proven R8-R10).
// INIT: 16-lane bitonic sort of the group's d values; worst = 11th-of-16
// (subset 11th >= global 11th -> sound upper bound, tighter than max-of-16).
#define PROCESS_BATCH(C, INIT)                                              \
  {                                                                         \
    const float cx = (C).x, cy = (C).y, cz = (C).z;                         \
    const int corig = __float_as_int((C).w);                                \
    const float csq = __fmaf_rn(cz, cz, __fmaf_rn(cy, cy,                   \
                                __fmul_rn(cx, cx)));                        \
    _Pragma("unroll")                                                       \
    for (int q = 0; q < WQ; ++q) {                                          \
      float dot = __fmul_rn(cx, qx[q]);                                     \
      dot = __fmaf_rn(cy, qy[q], dot);                                      \
      dot = __fmaf_rn(cz, qz[q], dot);                                      \
      const float sum = __fadd_rn(qsq[q], csq);                             \
      const float d = __fmaf_rn(dot, -2.0f, sum);                           \
      if (INIT) {                                                           \
        float sv = d;                                                       \
        const int l4 = lane & 15;                                           \
        _Pragma("unroll")                                                   \
        for (int k = 2; k <= 16; k <<= 1) {                                 \
          _Pragma("unroll")                                                 \
          for (int j = k >> 1; j >= 1; j >>= 1) {                           \
            const float ov = __shfl_xor(sv, j);                             \
            const bool keepmin = (((l4 & j) == 0) == ((l4 & k) == 0));      \
            sv = keepmin ? fminf(sv, ov) : fmaxf(sv, ov);                   \
          }                                                                 \
        }                                                                   \
        worst[q] = __int_as_float(__builtin_amdgcn_readlane(                \
            __float_as_int(sv), q * 16 + (KK - 1)));                        \
      }                                                                     \
      unsigned long long m = __ballot(d <= worst[q]);                       \
      while (m) {                                                           \
        const int sl = (int)__builtin_ctzll(m);                             \
        m &= m - 1;                                                         \
        const float nd = __int_as_float(__builtin_amdgcn_readlane(          \
            __float_as_int(d), sl));                                        \
        if (nd <= worst[q]) {                                               \
          const int norig = __builtin_amdgcn_readlane(corig, sl);           \
          const float pld = __int_as_float(                                 \
              __builtin_amdgcn_ds_bpermute(upaddr, __float_as_int(ld)));    \
          const int pli = __builtin_amdgcn_ds_bpermute(upaddr, li);         \
          const bool gt = (ld > nd) || (ld == nd && li > norig);            \
          if (ingrp[q] && gt) {                                             \
            const bool pgt = (pld > nd) || (pld == nd && pli > norig);      \
            const bool fst = (lrank == 0) || (!pgt);                        \
            ld = fst ? nd : pld;                                            \
            li = fst ? norig : pli;                                         \
          }                                                                 \
          worst[q] = fminf(worst[q],                                        \
              __int_as_float(__builtin_amdgcn_readlane(                     \
                  __float_as_int(ld), q * 16 + (KK - 1))));                 \
        }                                                                   \
      }                                                                     \
    }                                                                       \
  }

#define WMAX4 fmaxf(fmaxf(worst[0], worst[1]), fmaxf(worst[2], worst[3]))

__global__ __launch_bounds__(NTHREADS) void knn_pool_kernel(
    const float* __restrict__ src_f, const float* __restrict__ tgt_f,
    const float4* __restrict__ cand, const float* __restrict__ aabb,
    int* __restrict__ ctr, float* __restrict__ out)
{
    const int tid = threadIdx.x, wave = tid >> 6, lane = tid & 63;
    const int lq = lane >> 4, lrank = lane & 15;
    const bool inlist = (lrank < KK);
    const int upaddr = ((lane + 63) & 63) << 2;   // ds_bpermute: lane-1

    __shared__ float sab[2][NTILES * 6];          // both instances, 6 KB
    __shared__ unsigned slist[NWAVES][NTILES];    // 2 KB
    for (int i = tid; i < 2 * NTILES * 6; i += NTHREADS)
        ((float*)sab)[i] = aabb[i];
    __syncthreads();

    while (true) {
        int chunk = 0;
        if (lane == 0) chunk = atomicAdd(ctr, 1);
        chunk = __shfl(chunk, 0);
        if (chunk >= NCHUNKS) break;
        const int inst = chunk >> 12;             // 4096 chunks / instance
        const int q0 = (chunk & 4095) * WQ;       // sorted row
        const float* __restrict__ feats = inst ? tgt_f : src_f;
        float* __restrict__ outb = out + (size_t)inst * N_PTS * (2 * C_FEAT);
        const float4* __restrict__ cd = cand + inst * N_PTS;
        const float* __restrict__ ab = sab[inst];

        float qx[WQ], qy[WQ], qz[WQ], qsq[WQ];
        int qor[WQ]; bool ingrp[WQ]; float worst[WQ];
        float wqmnx = FLT_MAX, wqmny = FLT_MAX, wqmnz = FLT_MAX;
        float wqmxx = -FLT_MAX, wqmxy = -FLT_MAX, wqmxz = -FLT_MAX;
        #pragma unroll
        for (int q = 0; q < WQ; ++q) {
            const float4 c = cd[q0 + q];
            qx[q] = c.x; qy[q] = c.y; qz[q] = c.z;
            qor[q] = __float_as_int(c.w);
            qsq[q] = __fmaf_rn(c.z, c.z, __fmaf_rn(c.y, c.y,
                     __fmul_rn(c.x, c.x)));
            ingrp[q] = inlist && (lq == q);
            worst[q] = FLT_MAX;
            wqmnx = fminf(wqmnx, c.x); wqmxx = fmaxf(wqmxx, c.x);
            wqmny = fminf(wqmny, c.y); wqmxy = fmaxf(wqmxy, c.y);
            wqmnz = fminf(wqmnz, c.z); wqmxz = fmaxf(wqmxz, c.z);
        }

        float ld = FLT_MAX;   // lane-distributed list (lex (d, orig_idx))
        int   li = 0x7fffffff;

        const int ownt = q0 / TILE;   // tile containing the queries

        // ---- own tile first (seed on batch 0, tighten via batch 1) ----
        {
            const float4 c0 = cd[ownt * TILE + lane];
            const float4 c1 = cd[ownt * TILE + 64 + lane];
            PROCESS_BATCH(c0, true);
            PROCESS_BATCH(c1, false);
        }
        const float wmax0 = WMAX4;

        // ---- zigzag survivor build (packed (lb & ~0xFF) | tile) ----
        int nsurv = 0;
        #pragma unroll
        for (int g = 0; g < 4; ++g) {
            const int p = g * 64 + lane;
            const int o = (p >> 1) + 1;
            const int t = (p & 1) ? (ownt - o) : (ownt + o);
            bool ok = (t >= 0) && (t < NTILES);
            float lb = 0.0f;
            if (ok) {
                const float dx = fmaxf(0.f, fmaxf(ab[t*6+0] - wqmxx, wqmnx - ab[t*6+3]));
                const float dy = fmaxf(0.f, fmaxf(ab[t*6+1] - wqmxy, wqmny - ab[t*6+4]));
                const float dz = fmaxf(0.f, fmaxf(ab[t*6+2] - wqmxz, wqmnz - ab[t*6+5]));
                lb = dx * dx;
                lb = fmaf(dy, dy, lb);
                lb = fmaf(dz, dz, lb);
                ok = (lb - 1e-3f) <= wmax0;   // margin >> fp32 chain error
            }
            const unsigned long long mk = __ballot(ok);
            if (ok) {
                const int idx = nsurv + (int)__popcll(mk & ((1ull << lane) - 1ull));
                slist[wave][idx] = (__float_as_uint(lb) & 0xFFFFFF00u)
                                   | (unsigned)t;
            }
            nsurv += (int)__popcll(mk);
        }

        // ---- sort first <=64 survivors by lb (64-lane bitonic, u32) ----
        {
            unsigned e = (lane < nsurv) ? slist[wave][lane] : SENT32;
            #pragma unroll
            for (int k = 2; k <= 64; k <<= 1) {
                #pragma unroll
                for (int j = k >> 1; j >= 1; j >>= 1) {
                    const unsigned ov = (unsigned)__shfl_xor((int)e, j);
                    const bool keepmin = (((lane & j) == 0) == ((lane & k) == 0));
                    e = keepmin ? min(e, ov) : max(e, ov);
                }
            }
            if (lane < nsurv && lane < 64) slist[wave][lane] = e;
        }
        const bool canbreak = (nsurv <= 64);   // sorted => lb ascending

        // ---- ascending-lb scan: ping-pong prefetch + live recheck ----
        float4 A0, A1, B0, B1;
        unsigned uA = 0, uB = 0;
        {
            uA = (0 < nsurv) ? slist[wave][0] : (unsigned)ownt;
            const int ta = (int)(uA & 0xFFu);
            A0 = cd[ta * TILE + lane]; A1 = cd[ta * TILE + 64 + lane];
            uB = (1 < nsurv) ? slist[wave][1] : (unsigned)ownt;
            const int tb = (int)(uB & 0xFFu);
            B0 = cd[tb * TILE + lane]; B1 = cd[tb * TILE + 64 + lane];
        }
        int s = 0;
        while (s < nsurv) {
            {
                const unsigned uN = (s + 2 < nsurv) ? slist[wave][s + 2]
                                                    : (unsigned)ownt;
                const int tn = (int)(uN & 0xFFu);
                if (__uint_as_float(uA & 0xFFFFFF00u) - 1e-3f <= WMAX4) {
                    PROCESS_BATCH(A0, false);
                    PROCESS_BATCH(A1, false);
                } else if (canbreak) break;
                uA = uN;
                A0 = cd[tn * TILE + lane]; A1 = cd[tn * TILE + 64 + lane];
                ++s;
                if (s >= nsurv) break;
            }
            {
                const unsigned uN = (s + 2 < nsurv) ? slist[wave][s + 2]
                                                    : (unsigned)ownt;
                const int tn = (int)(uN & 0xFFu);
                if (__uint_as_float(uB & 0xFFFFFF00u) - 1e-3f <= WMAX4) {
                    PROCESS_BATCH(B0, false);
                    PROCESS_BATCH(B1, false);
                } else if (canbreak) break;
                uB = uN;
                B0 = cd[tn * TILE + lane]; B1 = cd[tn * TILE + 64 + lane];
                ++s;
            }
        }

        // Rank 0 (lex-smallest: self or -1ulp near-twin) dropped
        // positionally. Ranks 1..10 -> feature columns 0..9.
        float fv = -FLT_MAX;
        if (inlist && lrank >= 1)
            fv = feats[(size_t)li * C_FEAT + (lrank - 1)];
        #pragma unroll
        for (int off = 1; off < 16; off <<= 1)
            fv = fmaxf(fv, __shfl_xor(fv, off));

        #pragma unroll
        for (int q = 0; q < WQ; ++q) {
            const float M   = __shfl(fv, q * 16);
            const int   row = qor[q];
            const float v   = feats[(size_t)row * C_FEAT + lane];
            outb[(size_t)row * (2 * C_FEAT) + lane]          = v;
            outb[(size_t)row * (2 * C_FEAT) + C_FEAT + lane] = M - v;
        }
    }
}

extern "C" void kernel_launch(void* const* d_in, const int* in_sizes, int n_in,
                              void* d_out, int out_size, void* d_ws, size_t ws_size,
                              hipStream_t stream) {
    const float* src_f = (const float*)d_in[0];
    const float* tgt_f = (const float*)d_in[1];
    const float* src_c = (const float*)d_in[2];
    const float* tgt_c = (const float*)d_in[3];
    float* out = (float*)d_out;

    char* ws = (char*)d_ws;
    float4* cand = (float4*)(ws + WS_CAND);
    float*  aabb = (float*) (ws + WS_AABB);
    int*    ctr  = (int*)   (ws + WS_CTR);

    hipMemsetAsync(ctr, 0, 8, stream);
    hipLaunchKernelGGL(sort_kernel, dim3(2), dim3(1024), 0, stream,
                       src_c, tgt_c, cand);
    hipLaunchKernelGGL(aabb_kernel, dim3(2 * NTILES), dim3(64), 0, stream,
                       cand, aabb);
    // Persistent: 2048 blocks (8/CU), waves pull 4-query chunks from ctr.
    hipLaunchKernelGGL(knn_pool_kernel, dim3(2048), dim3(NTHREADS), 0, stream,
                       src_f, tgt_f, cand, aabb, ctr, out);
}

// Round 14
// 305.264 us; speedup vs baseline: 1.7246x; 1.1136x over previous
//
#include <hip/hip_runtime.h>
#include <cfloat>
#include <math.h>

// Exact-replication KNN (k=10, +self) + rank-column gather max-pool.
// NUMERICS FROZEN (R3 pass, absmax 0.0): fp32 chains
//   sq  = fma(z,z, fma(y,y, rn(x*x)))
//   dot = fma(z,z', fma(y,y', rn(x*x')))
//   d   = fma(dot, -2, rn(sq_i+sq_j))    [== rn(sum - rn(2*dot)), 2*dot exact]
// Selection order = jax top_k = ascending lexicographic (d, orig_idx) —
// proven order-independent in R8-R10 (absmax 0.0, nondeterministic sort).
//
// Round 14: fix R13's queue (which degenerated: 8192 chunks / 8192 waves =
// 1 chunk each = no balancing, plus a t=0 same-address atomic burst).
//  - WQ=2 -> 16384 chunks for 8192 waves (avg 2/wave, real refill).
//  - First chunk STATIC (= global wave id, no atomic, keeps locality);
//    refill claims staggered by completion -> no serialization burst.
//  - Seed = 11th-of-64 via full 64-lane bitonic on batch 0 (subset 11th >=
//    global 11th, sound) -> tighter initial gate.
// Pop/insert machinery and epilogue unchanged (proven); 16->32 lane groups.

#define N_PTS    16384
#define C_FEAT   64
#define KK       11
#define NCELLS   4096                 // 16^3 Morton cells
#define TILE     128                  // sorted points per tile
#define NTILES   (N_PTS / TILE)       // 128
#define WQ       2
#define NWAVES   4
#define NTHREADS (NWAVES * 64)
#define NCHUNKS  (2 * (N_PTS / WQ))   // 16384 (8192 per instance)
#define NSTATIC  8192                 // = total waves; chunks 0..8191 static
#define SENT32   0xFFFFFFFFu

// d_ws layout (bytes)
#define WS_CAND  0                          // float4[2][N_PTS]   512 KB
#define WS_AABB  (WS_CAND + 2*N_PTS*16)     // float[2][NTILES][6] 6 KB
#define WS_CTR   (WS_AABB + 2*NTILES*6*4)   // int                 8 B

__device__ __forceinline__ int cell_of(float x, float y, float z) {
    int cx = (int)floorf((x + 4.5f) * (16.0f / 9.0f));
    int cy = (int)floorf((y + 4.5f) * (16.0f / 9.0f));
    int cz = (int)floorf((z + 4.5f) * (16.0f / 9.0f));
    cx = min(15, max(0, cx));
    cy = min(15, max(0, cy));
    cz = min(15, max(0, cz));
    int m = 0;
    #pragma unroll
    for (int b = 0; b < 4; ++b)
        m |= (((cx >> b) & 1) << (3 * b)) |
             (((cy >> b) & 1) << (3 * b + 1)) |
             (((cz >> b) & 1) << (3 * b + 2));
    return m;
}

// Fused hist + scan + scatter. One block per instance, 1024 threads.
__global__ __launch_bounds__(1024) void sort_kernel(
    const float* __restrict__ src_c, const float* __restrict__ tgt_c,
    float4* __restrict__ cand)
{
    const int inst = blockIdx.x;
    const float* __restrict__ coords = inst ? tgt_c : src_c;
    float4* __restrict__ cb = cand + inst * N_PTS;

    __shared__ int hist[NCELLS];   // becomes running write-pointer after scan
    __shared__ int sd[1024];
    const int t = threadIdx.x;

    for (int i = t; i < NCELLS; i += 1024) hist[i] = 0;
    __syncthreads();

    int mycell[16];
    #pragma unroll
    for (int j = 0; j < 16; ++j) {
        const int p = j * 1024 + t;
        const float* c = coords + (size_t)p * 3;
        mycell[j] = cell_of(c[0], c[1], c[2]);
        atomicAdd(&hist[mycell[j]], 1);
    }
    __syncthreads();

    int v[4], ssum = 0;
    #pragma unroll
    for (int j = 0; j < 4; ++j) { v[j] = hist[t * 4 + j]; ssum += v[j]; }
    sd[t] = ssum;
    __syncthreads();
    for (int off = 1; off < 1024; off <<= 1) {
        const int x = (t >= off) ? sd[t - off] : 0;
        __syncthreads();
        sd[t] += x;
        __syncthreads();
    }
    int base = sd[t] - ssum;
    #pragma unroll
    for (int j = 0; j < 4; ++j) { hist[t * 4 + j] = base; base += v[j]; }
    __syncthreads();

    #pragma unroll
    for (int j = 0; j < 16; ++j) {
        const int p = j * 1024 + t;
        const float* c = coords + (size_t)p * 3;
        const int dst = atomicAdd(&hist[mycell[j]], 1);
        cb[dst] = make_float4(c[0], c[1], c[2], __int_as_float(p));
    }
}

__global__ void aabb_kernel(const float4* __restrict__ cand,
                            float* __restrict__ aabb) {
    const int it = blockIdx.x;                 // inst*NTILES + tile
    const int base = (it / NTILES) * N_PTS + (it % NTILES) * TILE;
    const int lane = threadIdx.x;              // 64 threads, 2 pts each
    float4 a = cand[base + lane], b = cand[base + 64 + lane];
    float mnx = fminf(a.x, b.x), mny = fminf(a.y, b.y), mnz = fminf(a.z, b.z);
    float mxx = fmaxf(a.x, b.x), mxy = fmaxf(a.y, b.y), mxz = fmaxf(a.z, b.z);
    #pragma unroll
    for (int off = 1; off < 64; off <<= 1) {
        mnx = fminf(mnx, __shfl_xor(mnx, off));
        mny = fminf(mny, __shfl_xor(mny, off));
        mnz = fminf(mnz, __shfl_xor(mnz, off));
        mxx = fmaxf(mxx, __shfl_xor(mxx, off));
        mxy = fmaxf(mxy, __shfl_xor(mxy, off));
        mxz = fmaxf(mxz, __shfl_xor(mxz, off));
    }
    if (lane == 0) {
        aabb[it * 6 + 0] = mnx; aabb[it * 6 + 1] = mny; aabb[it * 6 + 2] = mnz;
        aabb[it * 6 + 3] = mxx; aabb[it * 6 + 4] = mxy; aabb[it * 6 + 5] = mxz;
    }
}

// One 64-candidate batch vs the wave's 2 queries (pop/insert proven R8-R10).
// INIT: full 64-lane bitonic sort of d -> worst[q] = 11th-of-64 (sound:
// subset 11th >= global 11th).
#define PROCESS_BATCH(C, INIT)                                              \
  {                                                                         \
    const float cx = (C).x, cy = (C).y, cz = (C).z;                         \
    const int corig = __float_as_int((C).w);                                \
    const float csq = __fmaf_rn(cz, cz, __fmaf_rn(cy, cy,                   \
                                __fmul_rn(cx, cx)));                        \
    _Pragma("unroll")                                                       \
    for (int q = 0; q < WQ; ++q) {                                          \
      float dot = __fmul_rn(cx, qx[q]);                                     \
      dot = __fmaf_rn(cy, qy[q], dot);                                      \
      dot = __fmaf_rn(cz, qz[q], dot);                                      \
      const float sum = __fadd_rn(qsq[q], csq);                             \
      const float d = __fmaf_rn(dot, -2.0f, sum);                           \
      if (INIT) {                                                           \
        float sv = d;                                                       \
        _Pragma("unroll")                                                   \
        for (int k = 2; k <= 64; k <<= 1) {                                 \
          _Pragma("unroll")                                                 \
          for (int j = k >> 1; j >= 1; j >>= 1) {                           \
            const float ov = __shfl_xor(sv, j);                             \
            const bool keepmin = (((lane & j) == 0) == ((lane & k) == 0));  \
            sv = keepmin ? fminf(sv, ov) : fmaxf(sv, ov);                   \
          }                                                                 \
        }                                                                   \
        worst[q] = __int_as_float(__builtin_amdgcn_readlane(                \
            __float_as_int(sv), KK - 1));                                   \
      }                                                                     \
      unsigned long long m = __ballot(d <= worst[q]);                       \
      while (m) {                                                           \
        const int sl = (int)__builtin_ctzll(m);                             \
        m &= m - 1;                                                         \
        const float nd = __int_as_float(__builtin_amdgcn_readlane(          \
            __float_as_int(d), sl));                                        \
        if (nd <= worst[q]) {                                               \
          const int norig = __builtin_amdgcn_readlane(corig, sl);           \
          const float pld = __int_as_float(                                 \
              __builtin_amdgcn_ds_bpermute(upaddr, __float_as_int(ld)));    \
          const int pli = __builtin_amdgcn_ds_bpermute(upaddr, li);         \
          const bool gt = (ld > nd) || (ld == nd && li > norig);            \
          if (ingrp[q] && gt) {                                             \
            const bool pgt = (pld > nd) || (pld == nd && pli > norig);      \
            const bool fst = (lrank == 0) || (!pgt);                        \
            ld = fst ? nd : pld;                                            \
            li = fst ? norig : pli;                                         \
          }                                                                 \
          worst[q] = fminf(worst[q],                                        \
              __int_as_float(__builtin_amdgcn_readlane(                     \
                  __float_as_int(ld), q * 32 + (KK - 1))));                 \
        }                                                                   \
      }                                                                     \
    }                                                                       \
  }

#define WMAX2 fmaxf(worst[0], worst[1])

__global__ __launch_bounds__(NTHREADS) void knn_pool_kernel(
    const float* __restrict__ src_f, const float* __restrict__ tgt_f,
    const float4* __restrict__ cand, const float* __restrict__ aabb,
    int* __restrict__ ctr, float* __restrict__ out)
{
    const int tid = threadIdx.x, wave = tid >> 6, lane = tid & 63;
    const int lq = lane >> 5, lrank = lane & 31;    // 2 groups of 32
    const bool inlist = (lrank < KK);
    const int upaddr = ((lane + 63) & 63) << 2;     // ds_bpermute: lane-1

    __shared__ float sab[2][NTILES * 6];            // both instances, 6 KB
    __shared__ unsigned slist[NWAVES][NTILES];      // 2 KB
    for (int i = tid; i < 2 * NTILES * 6; i += NTHREADS)
        ((float*)sab)[i] = aabb[i];
    __syncthreads();

    // First chunk static (global wave id); refills from the atomic queue.
    int chunk = blockIdx.x * NWAVES + wave;
    while (chunk < NCHUNKS) {
        const int inst = chunk >> 13;               // 8192 chunks / instance
        const int q0 = (chunk & 8191) * WQ;         // sorted row
        const float* __restrict__ feats = inst ? tgt_f : src_f;
        float* __restrict__ outb = out + (size_t)inst * N_PTS * (2 * C_FEAT);
        const float4* __restrict__ cd = cand + inst * N_PTS;
        const float* __restrict__ ab = sab[inst];

        float qx[WQ], qy[WQ], qz[WQ], qsq[WQ];
        int qor[WQ]; bool ingrp[WQ]; float worst[WQ];
        float wqmnx = FLT_MAX, wqmny = FLT_MAX, wqmnz = FLT_MAX;
        float wqmxx = -FLT_MAX, wqmxy = -FLT_MAX, wqmxz = -FLT_MAX;
        #pragma unroll
        for (int q = 0; q < WQ; ++q) {
            const float4 c = cd[q0 + q];
            qx[q] = c.x; qy[q] = c.y; qz[q] = c.z;
            qor[q] = __float_as_int(c.w);
            qsq[q] = __fmaf_rn(c.z, c.z, __fmaf_rn(c.y, c.y,
                     __fmul_rn(c.x, c.x)));
            ingrp[q] = inlist && (lq == q);
            worst[q] = FLT_MAX;
            wqmnx = fminf(wqmnx, c.x); wqmxx = fmaxf(wqmxx, c.x);
            wqmny = fminf(wqmny, c.y); wqmxy = fmaxf(wqmxy, c.y);
            wqmnz = fminf(wqmnz, c.z); wqmxz = fmaxf(wqmxz, c.z);
        }

        float ld = FLT_MAX;   // lane-distributed list (lex (d, orig_idx))
        int   li = 0x7fffffff;

        const int ownt = q0 / TILE;   // tile containing the queries

        // ---- own tile first (seed on batch 0, tighten via batch 1) ----
        {
            const float4 c0 = cd[ownt * TILE + lane];
            const float4 c1 = cd[ownt * TILE + 64 + lane];
            PROCESS_BATCH(c0, true);
            PROCESS_BATCH(c1, false);
        }
        const float wmax0 = WMAX2;

        // ---- zigzag survivor build (packed (lb & ~0xFF) | tile) ----
        int nsurv = 0;
        #pragma unroll
        for (int g = 0; g < 4; ++g) {
            const int p = g * 64 + lane;
            const int o = (p >> 1) + 1;
            const int t = (p & 1) ? (ownt - o) : (ownt + o);
            bool ok = (t >= 0) && (t < NTILES);
            float lb = 0.0f;
            if (ok) {
                const float dx = fmaxf(0.f, fmaxf(ab[t*6+0] - wqmxx, wqmnx - ab[t*6+3]));
                const float dy = fmaxf(0.f, fmaxf(ab[t*6+1] - wqmxy, wqmny - ab[t*6+4]));
                const float dz = fmaxf(0.f, fmaxf(ab[t*6+2] - wqmxz, wqmnz - ab[t*6+5]));
                lb = dx * dx;
                lb = fmaf(dy, dy, lb);
                lb = fmaf(dz, dz, lb);
                ok = (lb - 1e-3f) <= wmax0;   // margin >> fp32 chain error
            }
            const unsigned long long mk = __ballot(ok);
            if (ok) {
                const int idx = nsurv + (int)__popcll(mk & ((1ull << lane) - 1ull));
                slist[wave][idx] = (__float_as_uint(lb) & 0xFFFFFF00u)
                                   | (unsigned)t;
            }
            nsurv += (int)__popcll(mk);
        }

        // ---- sort first <=64 survivors by lb (64-lane bitonic, u32) ----
        {
            unsigned e = (lane < nsurv) ? slist[wave][lane] : SENT32;
            #pragma unroll
            for (int k = 2; k <= 64; k <<= 1) {
                #pragma unroll
                for (int j = k >> 1; j >= 1; j >>= 1) {
                    const unsigned ov = (unsigned)__shfl_xor((int)e, j);
                    const bool keepmin = (((lane & j) == 0) == ((lane & k) == 0));
                    e = keepmin ? min(e, ov) : max(e, ov);
                }
            }
            if (lane < nsurv && lane < 64) slist[wave][lane] = e;
        }
        const bool canbreak = (nsurv <= 64);   // sorted => lb ascending

        // ---- ascending-lb scan: ping-pong prefetch + live recheck ----
        float4 A0, A1, B0, B1;
        unsigned uA = 0, uB = 0;
        {
            uA = (0 < nsurv) ? slist[wave][0] : (unsigned)ownt;
            const int ta = (int)(uA & 0xFFu);
            A0 = cd[ta * TILE + lane]; A1 = cd[ta * TILE + 64 + lane];
            uB = (1 < nsurv) ? slist[wave][1] : (unsigned)ownt;
            const int tb = (int)(uB & 0xFFu);
            B0 = cd[tb * TILE + lane]; B1 = cd[tb * TILE + 64 + lane];
        }
        int s = 0;
        while (s < nsurv) {
            {
                const unsigned uN = (s + 2 < nsurv) ? slist[wave][s + 2]
                                                    : (unsigned)ownt;
                const int tn = (int)(uN & 0xFFu);
                if (__uint_as_float(uA & 0xFFFFFF00u) - 1e-3f <= WMAX2) {
                    PROCESS_BATCH(A0, false);
                    PROCESS_BATCH(A1, false);
                } else if (canbreak) break;
                uA = uN;
                A0 = cd[tn * TILE + lane]; A1 = cd[tn * TILE + 64 + lane];
                ++s;
                if (s >= nsurv) break;
            }
            {
                const unsigned uN = (s + 2 < nsurv) ? slist[wave][s + 2]
                                                    : (unsigned)ownt;
                const int tn = (int)(uN & 0xFFu);
                if (__uint_as_float(uB & 0xFFFFFF00u) - 1e-3f <= WMAX2) {
                    PROCESS_BATCH(B0, false);
                    PROCESS_BATCH(B1, false);
                } else if (canbreak) break;
                uB = uN;
                B0 = cd[tn * TILE + lane]; B1 = cd[tn * TILE + 64 + lane];
                ++s;
            }
        }

        // Rank 0 (lex-smallest: self or -1ulp near-twin) dropped
        // positionally. Ranks 1..10 -> feature columns 0..9.
        float fv = -FLT_MAX;
        if (inlist && lrank >= 1)
            fv = feats[(size_t)li * C_FEAT + (lrank - 1)];
        #pragma unroll
        for (int off = 1; off < 32; off <<= 1)
            fv = fmaxf(fv, __shfl_xor(fv, off));

        #pragma unroll
        for (int q = 0; q < WQ; ++q) {
            const float M   = __shfl(fv, q * 32);
            const int   row = qor[q];
            const float v   = feats[(size_t)row * C_FEAT + lane];
            outb[(size_t)row * (2 * C_FEAT) + lane]          = v;
            outb[(size_t)row * (2 * C_FEAT) + C_FEAT + lane] = M - v;
        }

        // ---- refill from queue (staggered; no t=0 burst) ----
        int nxt = 0;
        if (lane == 0) nxt = NSTATIC + atomicAdd(ctr, 1);
        chunk = __shfl(nxt, 0);
    }
}

extern "C" void kernel_launch(void* const* d_in, const int* in_sizes, int n_in,
                              void* d_out, int out_size, void* d_ws, size_t ws_size,
                              hipStream_t stream) {
    const float* src_f = (const float*)d_in[0];
    const float* tgt_f = (const float*)d_in[1];
    const float* src_c = (const float*)d_in[2];
    const float* tgt_c = (const float*)d_in[3];
    float* out = (float*)d_out;

    char* ws = (char*)d_ws;
    float4* cand = (float4*)(ws + WS_CAND);
    float*  aabb = (float*) (ws + WS_AABB);
    int*    ctr  = (int*)   (ws + WS_CTR);

    hipMemsetAsync(ctr, 0, 8, stream);
    hipLaunchKernelGGL(sort_kernel, dim3(2), dim3(1024), 0, stream,
                       src_c, tgt_c, cand);
    hipLaunchKernelGGL(aabb_kernel, dim3(2 * NTILES), dim3(64), 0, stream,
                       cand, aabb);
    // Persistent: 2048 blocks (8/CU, 8192 waves); first chunk static,
    // remaining 8192 chunks via staggered refill.
    hipLaunchKernelGGL(knn_pool_kernel, dim3(2048), dim3(NTHREADS), 0, stream,
                       src_f, tgt_f, cand, aabb, ctr, out);
}

// Round 15
// 236.149 us; speedup vs baseline: 2.2294x; 1.2927x over previous
//
#include <hip/hip_runtime.h>
#include <cfloat>
#include <math.h>

// Exact-replication KNN (k=10, +self) + rank-column gather max-pool.
// NUMERICS FROZEN (R3 pass, absmax 0.0): fp32 chains
//   sq  = fma(z,z, fma(y,y, rn(x*x)))
//   dot = fma(z,z', fma(y,y', rn(x*x')))
//   d   = fma(dot, -2, rn(sq_i+sq_j))    [== rn(sum - rn(2*dot)), 2*dot exact]
// Selection order = jax top_k = ascending lexicographic (d, orig_idx) —
// proven order-independent R8-R14 (absmax 0.0, nondeterministic sort).
//
// Round 15: R10's static schedule (WQ=4, 2048 blocks, one chunk/wave,
// ZERO global atomics — R13/R14 proved the atomic work queue costs ~100us
// of serialized same-address claims, 2x the tail it recovers) + the three
// busy-reducers proven in R13/R14 (busy 82 -> 60us):
//  - seed: 64-lane bitonic on own-tile batch 0 -> worst = 11th-of-64
//    (sound: subset 11th >= global 11th); much tighter than max-of-16.
//  - survivor list bitonic-sorted by lb -> ascending-lb scan.
//  - live recheck becomes early BREAK when nsurv<=64 (sound: lb ascending,
//    wmax monotone tightening).

#define N_PTS    16384
#define C_FEAT   64
#define KK       11
#define NCELLS   4096                 // 16^3 Morton cells
#define TILE     128                  // sorted points per tile
#define NTILES   (N_PTS / TILE)       // 128
#define WQ       4
#define NWAVES   4
#define NTHREADS (NWAVES * 64)
#define QPB      (NWAVES * WQ)        // 16 queries per block
#define SENT32   0xFFFFFFFFu

// d_ws layout (bytes)
#define WS_CAND  0                          // float4[2][N_PTS]   512 KB
#define WS_AABB  (WS_CAND + 2*N_PTS*16)     // float[2][NTILES][6] 6 KB

__device__ __forceinline__ int cell_of(float x, float y, float z) {
    int cx = (int)floorf((x + 4.5f) * (16.0f / 9.0f));
    int cy = (int)floorf((y + 4.5f) * (16.0f / 9.0f));
    int cz = (int)floorf((z + 4.5f) * (16.0f / 9.0f));
    cx = min(15, max(0, cx));
    cy = min(15, max(0, cy));
    cz = min(15, max(0, cz));
    int m = 0;
    #pragma unroll
    for (int b = 0; b < 4; ++b)
        m |= (((cx >> b) & 1) << (3 * b)) |
             (((cy >> b) & 1) << (3 * b + 1)) |
             (((cz >> b) & 1) << (3 * b + 2));
    return m;
}

// Fused hist + scan + scatter. One block per instance, 1024 threads.
__global__ __launch_bounds__(1024) void sort_kernel(
    const float* __restrict__ src_c, const float* __restrict__ tgt_c,
    float4* __restrict__ cand)
{
    const int inst = blockIdx.x;
    const float* __restrict__ coords = inst ? tgt_c : src_c;
    float4* __restrict__ cb = cand + inst * N_PTS;

    __shared__ int hist[NCELLS];   // becomes running write-pointer after scan
    __shared__ int sd[1024];
    const int t = threadIdx.x;

    for (int i = t; i < NCELLS; i += 1024) hist[i] = 0;
    __syncthreads();

    int mycell[16];
    #pragma unroll
    for (int j = 0; j < 16; ++j) {
        const int p = j * 1024 + t;
        const float* c = coords + (size_t)p * 3;
        mycell[j] = cell_of(c[0], c[1], c[2]);
        atomicAdd(&hist[mycell[j]], 1);
    }
    __syncthreads();

    int v[4], ssum = 0;
    #pragma unroll
    for (int j = 0; j < 4; ++j) { v[j] = hist[t * 4 + j]; ssum += v[j]; }
    sd[t] = ssum;
    __syncthreads();
    for (int off = 1; off < 1024; off <<= 1) {
        const int x = (t >= off) ? sd[t - off] : 0;
        __syncthreads();
        sd[t] += x;
        __syncthreads();
    }
    int base = sd[t] - ssum;
    #pragma unroll
    for (int j = 0; j < 4; ++j) { hist[t * 4 + j] = base; base += v[j]; }
    __syncthreads();

    #pragma unroll
    for (int j = 0; j < 16; ++j) {
        const int p = j * 1024 + t;
        const float* c = coords + (size_t)p * 3;
        const int dst = atomicAdd(&hist[mycell[j]], 1);
        cb[dst] = make_float4(c[0], c[1], c[2], __int_as_float(p));
    }
}

__global__ void aabb_kernel(const float4* __restrict__ cand,
                            float* __restrict__ aabb) {
    const int it = blockIdx.x;                 // inst*NTILES + tile
    const int base = (it / NTILES) * N_PTS + (it % NTILES) * TILE;
    const int lane = threadIdx.x;              // 64 threads, 2 pts each
    float4 a = cand[base + lane], b = cand[base + 64 + lane];
    float mnx = fminf(a.x, b.x), mny = fminf(a.y, b.y), mnz = fminf(a.z, b.z);
    float mxx = fmaxf(a.x, b.x), mxy = fmaxf(a.y, b.y), mxz = fmaxf(a.z, b.z);
    #pragma unroll
    for (int off = 1; off < 64; off <<= 1) {
        mnx = fminf(mnx, __shfl_xor(mnx, off));
        mny = fminf(mny, __shfl_xor(mny, off));
        mnz = fminf(mnz, __shfl_xor(mnz, off));
        mxx = fmaxf(mxx, __shfl_xor(mxx, off));
        mxy = fmaxf(mxy, __shfl_xor(mxy, off));
        mxz = fmaxf(mxz, __shfl_xor(mxz, off));
    }
    if (lane == 0) {
        aabb[it * 6 + 0] = mnx; aabb[it * 6 + 1] = mny; aabb[it * 6 + 2] = mnz;
        aabb[it * 6 + 3] = mxx; aabb[it * 6 + 4] = mxy; aabb[it * 6 + 5] = mxz;
    }
}

// One 64-candidate batch vs the wave's 4 queries (pop/insert proven R8-R14).
// INIT: per-q 64-lane bitonic sort of d -> worst[q] = 11th-of-64 (sound:
// subset 11th >= global 11th; proven R14, absmax 0.0).
#define PROCESS_BATCH(C, INIT)                                              \
  {                                                                         \
    const float cx = (C).x, cy = (C).y, cz = (C).z;                         \
    const int corig = __float_as_int((C).w);                                \
    const float csq = __fmaf_rn(cz, cz, __fmaf_rn(cy, cy,                   \
                                __fmul_rn(cx, cx)));                        \
    _Pragma("unroll")                                                       \
    for (int q = 0; q < WQ; ++q) {                                          \
      float dot = __fmul_rn(cx, qx[q]);                                     \
      dot = __fmaf_rn(cy, qy[q], dot);                                      \
      dot = __fmaf_rn(cz, qz[q], dot);                                      \
      const float sum = __fadd_rn(qsq[q], csq);                             \
      const float d = __fmaf_rn(dot, -2.0f, sum);                           \
      if (INIT) {                                                           \
        float sv = d;                                                       \
        _Pragma("unroll")                                                   \
        for (int k = 2; k <= 64; k <<= 1) {                                 \
          _Pragma("unroll")                                                 \
          for (int j = k >> 1; j >= 1; j >>= 1) {                           \
            const float ov = __shfl_xor(sv, j);                             \
            const bool keepmin = (((lane & j) == 0) == ((lane & k) == 0));  \
            sv = keepmin ? fminf(sv, ov) : fmaxf(sv, ov);                   \
          }                                                                 \
        }                                                                   \
        worst[q] = __int_as_float(__builtin_amdgcn_readlane(                \
            __float_as_int(sv), KK - 1));                                   \
      }                                                                     \
      unsigned long long m = __ballot(d <= worst[q]);                       \
      while (m) {                                                           \
        const int sl = (int)__builtin_ctzll(m);                             \
        m &= m - 1;                                                         \
        const float nd = __int_as_float(__builtin_amdgcn_readlane(          \
            __float_as_int(d), sl));                                        \
        if (nd <= worst[q]) {                                               \
          const int norig = __builtin_amdgcn_readlane(corig, sl);           \
          const float pld = __int_as_float(                                 \
              __builtin_amdgcn_ds_bpermute(upaddr, __float_as_int(ld)));    \
          const int pli = __builtin_amdgcn_ds_bpermute(upaddr, li);         \
          const bool gt = (ld > nd) || (ld == nd && li > norig);            \
          if (ingrp[q] && gt) {                                             \
            const bool pgt = (pld > nd) || (pld == nd && pli > norig);      \
            const bool fst = (lrank == 0) || (!pgt);                        \
            ld = fst ? nd : pld;                                            \
            li = fst ? norig : pli;                                         \
          }                                                                 \
          worst[q] = fminf(worst[q],                                        \
              __int_as_float(__builtin_amdgcn_readlane(                     \
                  __float_as_int(ld), q * 16 + (KK - 1))));                 \
        }                                                                   \
      }                                                                     \
    }                                                                       \
  }

#define WMAX4 fmaxf(fmaxf(worst[0], worst[1]), fmaxf(worst[2], worst[3]))

__global__ __launch_bounds__(NTHREADS) void knn_pool_kernel(
    const float* __restrict__ src_f, const float* __restrict__ tgt_f,
    const float4* __restrict__ cand, const float* __restrict__ aabb,
    float* __restrict__ out)
{
    const int inst = blockIdx.x & 1;
    const float* __restrict__ feats = inst ? tgt_f : src_f;
    float* __restrict__ outb = out + (size_t)inst * N_PTS * (2 * C_FEAT);
    const float4* __restrict__ cd = cand + inst * N_PTS;

    const int tid = threadIdx.x, wave = tid >> 6, lane = tid & 63;
    const int lq = lane >> 4, lrank = lane & 15;
    const bool inlist = (lrank < KK);
    const int upaddr = ((lane + 63) & 63) << 2;   // ds_bpermute: lane-1

    __shared__ float sab[NTILES * 6];             // 3 KB
    __shared__ unsigned slist[NWAVES][NTILES];    // 2 KB
    for (int i = tid; i < NTILES * 6; i += NTHREADS)
        sab[i] = aabb[inst * NTILES * 6 + i];
    __syncthreads();

    const int q0 = (blockIdx.x >> 1) * QPB + wave * WQ;  // sorted row
    float qx[WQ], qy[WQ], qz[WQ], qsq[WQ];
    int qor[WQ]; bool ingrp[WQ]; float worst[WQ];
    float wqmnx = FLT_MAX, wqmny = FLT_MAX, wqmnz = FLT_MAX;
    float wqmxx = -FLT_MAX, wqmxy = -FLT_MAX, wqmxz = -FLT_MAX;
    #pragma unroll
    for (int q = 0; q < WQ; ++q) {
        const float4 c = cd[q0 + q];
        qx[q] = c.x; qy[q] = c.y; qz[q] = c.z;
        qor[q] = __float_as_int(c.w);
        qsq[q] = __fmaf_rn(c.z, c.z, __fmaf_rn(c.y, c.y, __fmul_rn(c.x, c.x)));
        ingrp[q] = inlist && (lq == q);
        worst[q] = FLT_MAX;
        wqmnx = fminf(wqmnx, c.x); wqmxx = fmaxf(wqmxx, c.x);
        wqmny = fminf(wqmny, c.y); wqmxy = fmaxf(wqmxy, c.y);
        wqmnz = fminf(wqmnz, c.z); wqmxz = fmaxf(wqmxz, c.z);
    }

    float ld = FLT_MAX;   // lane-distributed sorted list (lex (d, orig_idx))
    int   li = 0x7fffffff;

    const int ownt = q0 / TILE;   // tile containing the queries

    // ---- own tile first: bitonic seed on batch 0, tighten via batch 1 ----
    {
        const float4 c0 = cd[ownt * TILE + lane];
        const float4 c1 = cd[ownt * TILE + 64 + lane];
        PROCESS_BATCH(c0, true);
        PROCESS_BATCH(c1, false);
    }
    const float wmax0 = WMAX4;

    // ---- zigzag survivor build (packed (lb & ~0xFF) | tile) ----
    int nsurv = 0;
    #pragma unroll
    for (int g = 0; g < 4; ++g) {
        const int p = g * 64 + lane;
        const int o = (p >> 1) + 1;
        const int t = (p & 1) ? (ownt - o) : (ownt + o);
        bool ok = (t >= 0) && (t < NTILES);
        float lb = 0.0f;
        if (ok) {
            const float dx = fmaxf(0.f, fmaxf(sab[t*6+0] - wqmxx, wqmnx - sab[t*6+3]));
            const float dy = fmaxf(0.f, fmaxf(sab[t*6+1] - wqmxy, wqmny - sab[t*6+4]));
            const float dz = fmaxf(0.f, fmaxf(sab[t*6+2] - wqmxz, wqmnz - sab[t*6+5]));
            lb = dx * dx;
            lb = fmaf(dy, dy, lb);
            lb = fmaf(dz, dz, lb);
            ok = (lb - 1e-3f) <= wmax0;   // margin >> fp32 chain error
        }
        const unsigned long long mk = __ballot(ok);
        if (ok) {
            const int idx = nsurv + (int)__popcll(mk & ((1ull << lane) - 1ull));
            slist[wave][idx] = (__float_as_uint(lb) & 0xFFFFFF00u) | (unsigned)t;
        }
        nsurv += (int)__popcll(mk);
    }

    // ---- sort first <=64 survivors by lb (64-lane bitonic, u32) ----
    {
        unsigned e = (lane < nsurv) ? slist[wave][lane] : SENT32;
        #pragma unroll
        for (int k = 2; k <= 64; k <<= 1) {
            #pragma unroll
            for (int j = k >> 1; j >= 1; j >>= 1) {
                const unsigned ov = (unsigned)__shfl_xor((int)e, j);
                const bool keepmin = (((lane & j) == 0) == ((lane & k) == 0));
                e = keepmin ? min(e, ov) : max(e, ov);
            }
        }
        if (lane < nsurv && lane < 64) slist[wave][lane] = e;
    }
    const bool canbreak = (nsurv <= 64);   // sorted => lb ascending

    // ---- ascending-lb scan: ping-pong prefetch + live recheck/break ----
    float4 A0, A1, B0, B1;
    unsigned uA = 0, uB = 0;
    {
        uA = (0 < nsurv) ? slist[wave][0] : (unsigned)ownt;
        const int ta = (int)(uA & 0xFFu);
        A0 = cd[ta * TILE + lane]; A1 = cd[ta * TILE + 64 + lane];
        uB = (1 < nsurv) ? slist[wave][1] : (unsigned)ownt;
        const int tb = (int)(uB & 0xFFu);
        B0 = cd[tb * TILE + lane]; B1 = cd[tb * TILE + 64 + lane];
    }
    int s = 0;
    while (s < nsurv) {
        {
            const unsigned uN = (s + 2 < nsurv) ? slist[wave][s + 2]
                                                : (unsigned)ownt;
            const int tn = (int)(uN & 0xFFu);
            if (__uint_as_float(uA & 0xFFFFFF00u) - 1e-3f <= WMAX4) {
                PROCESS_BATCH(A0, false);
                PROCESS_BATCH(A1, false);
            } else if (canbreak) break;
            uA = uN;
            A0 = cd[tn * TILE + lane]; A1 = cd[tn * TILE + 64 + lane];
            ++s;
            if (s >= nsurv) break;
        }
        {
            const unsigned uN = (s + 2 < nsurv) ? slist[wave][s + 2]
                                                : (unsigned)ownt;
            const int tn = (int)(uN & 0xFFu);
            if (__uint_as_float(uB & 0xFFFFFF00u) - 1e-3f <= WMAX4) {
                PROCESS_BATCH(B0, false);
                PROCESS_BATCH(B1, false);
            } else if (canbreak) break;
            uB = uN;
            B0 = cd[tn * TILE + lane]; B1 = cd[tn * TILE + 64 + lane];
            ++s;
        }
    }

    // Rank 0 (lex-smallest: self or -1ulp near-twin) dropped positionally.
    // Ranks 1..10 -> feature columns 0..9. li holds ORIGINAL indices.
    float fv = -FLT_MAX;
    if (inlist && lrank >= 1)
        fv = feats[(size_t)li * C_FEAT + (lrank - 1)];
    #pragma unroll
    for (int off = 1; off < 16; off <<= 1)
        fv = fmaxf(fv, __shfl_xor(fv, off));

    #pragma unroll
    for (int q = 0; q < WQ; ++q) {
        const float M   = __shfl(fv, q * 16);
        const int   row = qor[q];
        const float v   = feats[(size_t)row * C_FEAT + lane];
        outb[(size_t)row * (2 * C_FEAT) + lane]          = v;
        outb[(size_t)row * (2 * C_FEAT) + C_FEAT + lane] = M - v;
    }
}

extern "C" void kernel_launch(void* const* d_in, const int* in_sizes, int n_in,
                              void* d_out, int out_size, void* d_ws, size_t ws_size,
                              hipStream_t stream) {
    const float* src_f = (const float*)d_in[0];
    const float* tgt_f = (const float*)d_in[1];
    const float* src_c = (const float*)d_in[2];
    const float* tgt_c = (const float*)d_in[3];
    float* out = (float*)d_out;

    char* ws = (char*)d_ws;
    float4* cand = (float4*)(ws + WS_CAND);
    float*  aabb = (float*) (ws + WS_AABB);

    hipLaunchKernelGGL(sort_kernel, dim3(2), dim3(1024), 0, stream,
                       src_c, tgt_c, cand);
    hipLaunchKernelGGL(aabb_kernel, dim3(2 * NTILES), dim3(64), 0, stream,
                       cand, aabb);
    // Static schedule (R10): 2048 blocks, even=src odd=tgt, no atomics.
    hipLaunchKernelGGL(knn_pool_kernel, dim3(2 * (N_PTS / QPB)),
                       dim3(NTHREADS), 0, stream, src_f, tgt_f, cand, aabb, out);
}